// Round 4
// baseline (135.571 us; speedup 1.0000x reference)
//
#include <hip/hip_runtime.h>
#include <math.h>

#define NB 2048
#define DEPTH 8

// ws layout (float offsets)
#define FTAB_OFF    0        // sponge fused cs: 8*5*256*8 = 81920 floats
#define BF01_OFF    81920    // bf stages 0-1 packed: 256*3*2 float4 = 6144 floats
#define BFF_OFF     88064    // bf fused (2,3)..(10,11): 5*256*8 = 10240 floats
#define ACT4_OFF    98304    // act table: 2048 float4 = 8192 floats
#define PHYS_OFF    106496   // phys[4096] int
#define PHYSR_OFF   110592   // phys_recall[2048] int
#define PHYSO2_OFF  112640   // per-thread pre-gather [256*12] int
// total 115712 floats = 462848 bytes

// ---------------- precompute: cos/sin tables + activation constants ----------------
__global__ void tab_precompute(const float* __restrict__ angles,
                               const float* __restrict__ bf_angles,
                               const float* __restrict__ act_bias,
                               const float* __restrict__ act_curv,
                               float* __restrict__ ws) {
    int id = blockIdx.x * 256 + threadIdx.x;
    if (id < 40960) {
        // sponge fused table: id = ((d*5+g)*256 + t)*4 + w
        int w  = id & 3;
        int t  = (id >> 2) & 255;
        int dg = id >> 10;
        int d = dg / 5, g = dg - 5 * d;
        int a = 2 * (t & 127) + (t >> 7);
        int pair = (w == 0) ? a : (w == 1) ? (a + 256)
                 : (w == 2) ? (2 * a) : (2 * a + 1);
        int st = 2 * g + (w >> 1);
        float ang = angles[(d * 10 + st) * 512 + pair];
        float s, c; sincosf(ang, &s, &c);
        ws[FTAB_OFF + 2 * id]     = c;
        ws[FTAB_OFF + 2 * id + 1] = s;
    } else if (id < 44032) {
        // BF01: e = (t*3+i)*4 + w ; a = t+256i
        int e = id - 40960;
        int w = e & 3; int ti = e >> 2;
        int t = ti / 3; int i = ti - 3 * t;
        int a = t + 256 * i;
        int pair = (w == 0) ? a : (w == 1) ? (a + 768)
                 : (w == 2) ? (2 * a) : (2 * a + 1);
        int stage = (w < 2) ? 0 : 1;
        float ang = bf_angles[stage * 1536 + pair];
        float s, c; sincosf(ang, &s, &c);
        ws[BF01_OFF + 2 * e]     = c;
        ws[BF01_OFF + 2 * e + 1] = s;
    } else if (id < 49152) {
        // BFF: e = (f*256+t)*4 + w ; fused stages (2+2f, 3+2f)
        int e = id - 44032;
        int f = e >> 10; int rem = e & 1023; int t = rem >> 2; int w = rem & 3;
        int P;
        if (f == 0) P = 3 * t;
        else { int k = 8 - 2 * f; P = ((t >> (2 * f)) * (768 >> k)) + (t & ((256 >> k) - 1)); }
        int pair = (w == 0) ? P : (w == 1) ? (P + 768)
                 : (w == 2) ? (2 * P) : (2 * P + 1);
        int stage = (w < 2) ? (2 + 2 * f) : (3 + 2 * f);
        float ang = bf_angles[stage * 1536 + pair];
        float s, c; sincosf(ang, &s, &c);
        ws[BFF_OFF + 2 * e]     = c;
        ws[BFF_OFF + 2 * e + 1] = s;
    } else if (id < 51200) {
        int ida = id - 49152;              // d*256 + k
        float cu = act_curv[ida];
        float c  = 0.5f * (cu + sqrtf(cu * cu + 1.0f));
        ((float4*)(ws + ACT4_OFF))[ida] =
            make_float4(act_bias[ida], c, 1.0f / c, 0.0f);
    }
}

// ---------------- precompute: compacted mem slots + gather tables ------------------
__global__ void phys_precompute(const int* __restrict__ recall_idx,
                                const int* __restrict__ out_mem_idx,
                                float* __restrict__ ws) {
    __shared__ int physL[4096];
    int t = threadIdx.x;   // 1024 threads, 1 block
    for (int q = 0; q < 4; ++q) {
        int v = t + q * 1024;
        int p;
        for (;;) {
            int d = v >> 9, j = v & 511;
            if (d == 0)  { p = j; break; }
            if (j < 256) { p = 256 + d * 256 + j; break; }
            v = recall_idx[(d - 1) * 256 + (j - 256)];
        }
        physL[t + q * 1024] = p;
        ((int*)(ws + PHYS_OFF))[t + q * 1024] = p;
    }
    __syncthreads();
    for (int q = 0; q < 2; ++q) {
        int i = t + q * 1024;
        ((int*)(ws + PHYSR_OFF))[i] = physL[recall_idx[i]];
    }
    // pre-gather: thread tt, quad i (a = tt+256i), slot k: pos = tl+1536*th+384k
    for (int e = t; e < 3072; e += 1024) {
        int tt = e / 12; int r = e - 12 * tt; int i = r >> 2; int k = r & 3;
        int a = tt + 256 * i;
        int tl = a >> 1, th = a & 1;
        int pos = tl + 1536 * th + 384 * k;
        int val = (pos < 2048) ? physL[out_mem_idx[pos]] : (2304 + (pos - 2048));
        ((int*)(ws + PHYSO2_OFF))[e] = val;
    }
}

__device__ __forceinline__ float actf(float x, float c, float ic) {
    const float is2 = 0.70710678118654752f;
    float tt = 0.78539816339744831f * ic;
    float y0 = is2 * ic;
    float y1 = (is2 - 1.0f) * ic;
    float mid = ic * (is2 - __cosf(0.78539816339744831f + c * x));
    return x > tt ? (y0 + (x - tt)) : (x < -tt ? y1 : mid);
}

// conflict-free exchange swizzle: phys0=p0, phys[4:1]=p[5:2], phys5=p6^p1,
// phys6=p1, phys[9:7]=p[9:7]  (bijection on [0,1024))
__device__ __forceinline__ int swz(int p) {
    return (p & 1) | ((p & 0x3C) >> 1) | ((((p >> 6) ^ (p >> 1)) & 1) << 5)
         | (((p >> 1) & 1) << 6) | (p & 0x380);
}

// ---------------- main kernel ------------------------------------------------------
__launch_bounds__(256, 8)
__global__ void sponge_kernel(const float* __restrict__ X,
                              const float* __restrict__ scales,
                              const float* __restrict__ ws,
                              float* __restrict__ out) {
    __shared__ float lds[4352];          // 17408 B
    float* memb = lds;                   // [0,2304) compacted mem
    float* pb0  = lds + 2304;
    float* pb1  = lds + 3328;
    const int t   = threadIdx.x;
    const int row = blockIdx.x;

    const float4* bf01  = (const float4*)(ws + BF01_OFF);
    const float4* bff   = (const float4*)(ws + BFF_OFF);
    const float4* act4  = (const float4*)(ws + ACT4_OFF);
    const int* phys   = (const int*)(ws + PHYS_OFF);
    const int* physr  = (const int*)(ws + PHYSR_OFF);
    const int* physo2 = (const int*)(ws + PHYSO2_OFF);

    const int tl = t & 127, th = t >> 7;
    const int b  = tl + th * 512;        // holdings {b+128m}
    const int a  = 2 * tl + th;          // write base

    // fixed swizzled addresses
    const int wA0 = swz(2 * a), wA1 = swz(2 * a + 512);
    const int rd0 = swz(b), rd1 = swz(b + 128), rd2 = swz(b + 256), rd3 = swz(b + 384);
    const int zmem = swz(2 * t);
    const int u = t - 128;
    int za0 = 0, za1 = 0, za2 = 0, za3 = 0, zk0 = 0, zk1 = 0;
    if (t < 128) {
        int k0 = t >> 1;
        za0 = swz(512 + k0);       za1 = swz(512 + k0 + 64);
        za2 = swz(512 + k0 + 128); za3 = swz(512 + k0 + 192);
    } else {
        zk0 = swz(768 + u); zk1 = swz(896 + u);
    }

    float h0, h1, h2, h3;
    {
        const float* Xr = X + (size_t)row * 1024;
        h0 = Xr[b]       * scales[b];
        h1 = Xr[b + 128] * scales[b + 128];
        h2 = Xr[b + 256] * scales[b + 256];
        h3 = Xr[b + 384] * scales[b + 384];
    }

    float* wbuf = pb0;
    float* rbuf = pb1;
    const float4* ft = (const float4*)(ws + FTAB_OFF) + 2 * t;

    for (int d = 0; d < DEPTH; ++d) {
        for (int g = 0; g < 5; ++g) {
            float4 csA = ft[0], csB = ft[1]; ft += 512;
            float g0 =  csA.x * h0 + csA.y * h2;
            float g2 = -csA.y * h0 + csA.x * h2;
            float g1 =  csA.z * h1 + csA.w * h3;
            float g3 = -csA.w * h1 + csA.z * h3;
            float f0 =  csB.x * g0 + csB.y * g1;
            float f2 = -csB.y * g0 + csB.x * g1;
            float f1 =  csB.z * g2 + csB.w * g3;
            float f3 = -csB.w * g2 + csB.z * g3;
            *(float2*)(wbuf + wA0) = make_float2(f0, f1);
            *(float2*)(wbuf + wA1) = make_float2(f2, f3);
            { float* tmp = wbuf; wbuf = rbuf; rbuf = tmp; }
            __syncthreads();
            if (g < 4) {
                h0 = rbuf[rd0]; h1 = rbuf[rd1]; h2 = rbuf[rd2]; h3 = rbuf[rd3];
            }
        }
        // ---- repack ----
        const float* z = rbuf;
        float2 mv = *(const float2*)(z + zmem);          // logical (2t, 2t+1)
        int2 pm = ((const int2*)(phys + d * 512))[t];
        memb[pm.x] = mv.x;
        memb[pm.y] = mv.y;
        int r0 = 0, r1 = 0;
        if (t < 128) {
            float x10 = z[za0], x11 = z[za1], x12 = z[za2], x13 = z[za3];
            int k0 = t >> 1;
            float4 a0 = act4[d * 256 + k0];
            float4 a1 = act4[d * 256 + k0 + 64];
            float4 a2 = act4[d * 256 + k0 + 128];
            float4 a3 = act4[d * 256 + k0 + 192];
            float sgn = (t & 1) ? -1.0f : 1.0f;
            h0 = actf(sgn * (x10 + a0.x), a0.y, a0.z);
            h1 = actf(sgn * (x11 + a1.x), a1.y, a1.z);
            h2 = actf(sgn * (x12 + a2.x), a2.y, a2.z);
            h3 = actf(sgn * (x13 + a3.x), a3.y, a3.z);
        } else {
            h0 = z[zk0];
            h1 = z[zk1];
            r0 = physr[d * 256 + u];
            r1 = physr[d * 256 + u + 128];
        }
        __syncthreads();
        if (t >= 128) {
            h2 = memb[r0];
            h3 = memb[r1];
        }
    }

    // ---- build pre & stages 0-1 (registers, pruning-free full width) ----
    lds[2304 + b]       = h0;    // sponge region for gather (natural layout)
    lds[2304 + b + 128] = h1;
    lds[2304 + b + 256] = h2;
    lds[2304 + b + 384] = h3;
    __syncthreads();
    int4 pg0 = ((const int4*)(physo2 + t * 12))[0];
    int4 pg1 = ((const int4*)(physo2 + t * 12))[1];
    int4 pg2 = ((const int4*)(physo2 + t * 12))[2];
    float v[12];
    v[0] = lds[pg0.x]; v[1]  = lds[pg0.y]; v[2]  = lds[pg0.z]; v[3]  = lds[pg0.w];
    v[4] = lds[pg1.x]; v[5]  = lds[pg1.y]; v[6]  = lds[pg1.z]; v[7]  = lds[pg1.w];
    v[8] = lds[pg2.x]; v[9]  = lds[pg2.y]; v[10] = lds[pg2.z]; v[11] = lds[pg2.w];
    __syncthreads();
    float* buf = lds;
#pragma unroll
    for (int i = 0; i < 3; ++i) {
        float4 c01 = bf01[(t * 3 + i) * 2];
        float4 c23 = bf01[(t * 3 + i) * 2 + 1];
        float q0 = v[4 * i], q1 = v[4 * i + 1], q2 = v[4 * i + 2], q3 = v[4 * i + 3];
        float g0 =  c01.x * q0 + c01.y * q2;
        float g2 = -c01.y * q0 + c01.x * q2;
        float g1 =  c01.z * q1 + c01.w * q3;
        float g3 = -c01.w * q1 + c01.z * q3;
        float y0 =  c23.x * g0 + c23.y * g1;
        float y2 = -c23.y * g0 + c23.x * g1;
        float y1 =  c23.z * g2 + c23.w * g3;
        float y3 = -c23.w * g2 + c23.z * g3;
        *(float2*)(buf + 2 * t + 512 * i)        = make_float2(y0, y1);
        *(float2*)(buf + 2 * t + 512 * i + 1536) = make_float2(y2, y3);
    }
    __syncthreads();

    // ---- fused pruned double-stages (2,3) (4,5) (6,7) (8,9) ----
#pragma unroll
    for (int f = 0; f < 4; ++f) {
        int P;
        if (f == 0) P = 3 * t;
        else { const int k = 8 - 2 * f;
               P = ((t >> (2 * f)) * (768 >> k)) + (t & ((256 >> k) - 1)); }
        int base = (P >> 1) + (P & 1) * 1536;
        float4 csS = bff[(f * 256 + t) * 2];
        float4 csT = bff[(f * 256 + t) * 2 + 1];
        float x1p = buf[base], x1q = buf[base + 384];
        float x2p = buf[base + 768], x2q = buf[base + 1152];
        float o1P =  csS.x * x1p + csS.y * x2p;
        float o2P = -csS.y * x1p + csS.x * x2p;
        float o1Q =  csS.z * x1q + csS.w * x2q;
        float o2Q = -csS.w * x1q + csS.z * x2q;
        float y0 =  csT.x * o1P + csT.y * o1Q;
        float y2 = -csT.y * o1P + csT.x * o1Q;
        float y1 =  csT.z * o2P + csT.w * o2Q;
        float y3 = -csT.w * o2P + csT.z * o2Q;
        __syncthreads();
        *(float2*)(buf + 2 * P)        = make_float2(y0, y1);
        *(float2*)(buf + 2 * P + 1536) = make_float2(y2, y3);
        __syncthreads();
    }

    // ---- fused (10,11) + output store ----
    {
        int base = (t >> 1) + (t & 1) * 1536;
        float4 csS = bff[(4 * 256 + t) * 2];
        float4 csT = bff[(4 * 256 + t) * 2 + 1];
        float x1p = buf[base], x1q = buf[base + 384];
        float x2p = buf[base + 768], x2q = buf[base + 1152];
        float o1P =  csS.x * x1p + csS.y * x2p;
        float o2P = -csS.y * x1p + csS.x * x2p;
        float o1Q =  csS.z * x1q + csS.w * x2q;
        float o2Q = -csS.w * x1q + csS.z * x2q;
        float y0 = csT.x * o1P + csT.y * o1Q;
        float y1 = csT.z * o2P + csT.w * o2Q;
        *(float2*)(out + (size_t)row * 512 + 2 * t) = make_float2(y0, y1);
    }
}

extern "C" void kernel_launch(void* const* d_in, const int* in_sizes, int n_in,
                              void* d_out, int out_size, void* d_ws, size_t ws_size,
                              hipStream_t stream) {
    const float* X          = (const float*)d_in[0];
    const float* scales     = (const float*)d_in[1];
    const float* angles     = (const float*)d_in[2];
    const float* act_bias   = (const float*)d_in[3];
    // d_in[4] act_activation — unused by the reference
    const float* act_curv   = (const float*)d_in[5];
    const float* bf_angles  = (const float*)d_in[6];
    // d_in[7] shuffle_perm — structural perfect shuffle, hardcoded
    const int*   recall_idx  = (const int*)d_in[8];
    const int*   out_mem_idx = (const int*)d_in[9];
    // d_in[10] bf_perm — structural perfect shuffle, hardcoded

    float* ws = (float*)d_ws;   // 462848 bytes used

    tab_precompute<<<200, 256, 0, stream>>>(angles, bf_angles, act_bias, act_curv, ws);
    phys_precompute<<<1, 1024, 0, stream>>>(recall_idx, out_mem_idx, ws);
    sponge_kernel<<<NB, 256, 0, stream>>>(X, scales, ws, (float*)d_out);
}

// Round 5
// 122.269 us; speedup vs baseline: 1.1088x; 1.1088x over previous
//
#include <hip/hip_runtime.h>
#include <math.h>

#define NB 2048
#define DEPTH 8

// ws layout (float offsets)
#define FTAB_OFF    0        // sponge fused cs: 8*5*256*8 = 81920 floats
#define BF01_OFF    81920    // bf stages 0-1 packed: 256*3*2 float4 = 6144 floats
#define BFF_OFF     88064    // bf fused (2,3)..(10,11): 5*256*8 = 10240 floats
#define ACT4_OFF    98304    // act table: 2048 float4 = 8192 floats
#define PHYS_OFF    106496   // phys[4096] int
#define PHYSR_OFF   110592   // phys_recall[2048] int
#define PHYSO2_OFF  112640   // per-thread pre-gather [256*12] int
// total 115712 floats = 462848 bytes

// ---------------- precompute: cos/sin tables + activation constants ----------------
__global__ void tab_precompute(const float* __restrict__ angles,
                               const float* __restrict__ bf_angles,
                               const float* __restrict__ act_bias,
                               const float* __restrict__ act_curv,
                               float* __restrict__ ws) {
    int id = blockIdx.x * 256 + threadIdx.x;
    if (id < 40960) {
        // sponge fused table: id = ((d*5+g)*256 + t)*4 + w
        int w  = id & 3;
        int t  = (id >> 2) & 255;
        int dg = id >> 10;
        int d = dg / 5, g = dg - 5 * d;
        int a = 2 * (t & 127) + (t >> 7);
        int pair = (w == 0) ? a : (w == 1) ? (a + 256)
                 : (w == 2) ? (2 * a) : (2 * a + 1);
        int st = 2 * g + (w >> 1);
        float ang = angles[(d * 10 + st) * 512 + pair];
        float s, c; sincosf(ang, &s, &c);
        ws[FTAB_OFF + 2 * id]     = c;
        ws[FTAB_OFF + 2 * id + 1] = s;
    } else if (id < 44032) {
        // BF01: e = (t*3+i)*4 + w ; a = t+256i
        int e = id - 40960;
        int w = e & 3; int ti = e >> 2;
        int t = ti / 3; int i = ti - 3 * t;
        int a = t + 256 * i;
        int pair = (w == 0) ? a : (w == 1) ? (a + 768)
                 : (w == 2) ? (2 * a) : (2 * a + 1);
        int stage = (w < 2) ? 0 : 1;
        float ang = bf_angles[stage * 1536 + pair];
        float s, c; sincosf(ang, &s, &c);
        ws[BF01_OFF + 2 * e]     = c;
        ws[BF01_OFF + 2 * e + 1] = s;
    } else if (id < 49152) {
        // BFF: e = (f*256+t)*4 + w ; fused stages (2+2f, 3+2f)
        int e = id - 44032;
        int f = e >> 10; int rem = e & 1023; int t = rem >> 2; int w = rem & 3;
        int P;
        if (f == 0) P = 3 * t;
        else { int k = 8 - 2 * f; P = ((t >> (2 * f)) * (768 >> k)) + (t & ((256 >> k) - 1)); }
        int pair = (w == 0) ? P : (w == 1) ? (P + 768)
                 : (w == 2) ? (2 * P) : (2 * P + 1);
        int stage = (w < 2) ? (2 + 2 * f) : (3 + 2 * f);
        float ang = bf_angles[stage * 1536 + pair];
        float s, c; sincosf(ang, &s, &c);
        ws[BFF_OFF + 2 * e]     = c;
        ws[BFF_OFF + 2 * e + 1] = s;
    } else if (id < 51200) {
        int ida = id - 49152;              // d*256 + k
        float cu = act_curv[ida];
        float c  = 0.5f * (cu + sqrtf(cu * cu + 1.0f));
        ((float4*)(ws + ACT4_OFF))[ida] =
            make_float4(act_bias[ida], c, 1.0f / c, 0.0f);
    }
}

// ---------------- precompute: compacted mem slots + gather tables ------------------
__global__ void phys_precompute(const int* __restrict__ recall_idx,
                                const int* __restrict__ out_mem_idx,
                                float* __restrict__ ws) {
    __shared__ int physL[4096];
    int t = threadIdx.x;   // 1024 threads, 1 block
    for (int q = 0; q < 4; ++q) {
        int v = t + q * 1024;
        int p;
        for (;;) {
            int d = v >> 9, j = v & 511;
            if (d == 0)  { p = j; break; }
            if (j < 256) { p = 256 + d * 256 + j; break; }
            v = recall_idx[(d - 1) * 256 + (j - 256)];
        }
        physL[t + q * 1024] = p;
        ((int*)(ws + PHYS_OFF))[t + q * 1024] = p;
    }
    __syncthreads();
    for (int q = 0; q < 2; ++q) {
        int i = t + q * 1024;
        ((int*)(ws + PHYSR_OFF))[i] = physL[recall_idx[i]];
    }
    // pre-gather: thread tt, quad i (a = tt+256i), slot k: pos = tl+1536*th+384k
    for (int e = t; e < 3072; e += 1024) {
        int tt = e / 12; int r = e - 12 * tt; int i = r >> 2; int k = r & 3;
        int a = tt + 256 * i;
        int tl = a >> 1, th = a & 1;
        int pos = tl + 1536 * th + 384 * k;
        int val = (pos < 2048) ? physL[out_mem_idx[pos]] : (2304 + (pos - 2048));
        ((int*)(ws + PHYSO2_OFF))[e] = val;
    }
}

__device__ __forceinline__ float actf(float x, float c, float ic) {
    const float is2 = 0.70710678118654752f;
    float tt = 0.78539816339744831f * ic;
    float y0 = is2 * ic;
    float y1 = (is2 - 1.0f) * ic;
    float mid = ic * (is2 - __cosf(0.78539816339744831f + c * x));
    return x > tt ? (y0 + (x - tt)) : (x < -tt ? y1 : mid);
}

// exchange swizzle (bijection on [0,1024)): phys0=p0, phys[4:1]=p[5:2],
// phys5=p6^p1, phys6=p1, phys[9:7]=p[9:7]
__device__ __forceinline__ int swz(int p) {
    return (p & 1) | ((p & 0x3C) >> 1) | ((((p >> 6) ^ (p >> 1)) & 1) << 5)
         | (((p >> 1) & 1) << 6) | (p & 0x380);
}

// ---------------- main kernel: 2 rows per block ------------------------------------
__launch_bounds__(256, 4)
__global__ void sponge_kernel(const float* __restrict__ X,
                              const float* __restrict__ scales,
                              const float* __restrict__ ws,
                              float* __restrict__ out) {
    __shared__ float lds[8704];          // 34816 B -> 4 blocks/CU (8 rows/CU)
    float* L0 = lds;                     // row A base: memb [0,2304) exch [2304,4352)
    float* L1 = lds + 4352;              // row B base
    const int t = threadIdx.x;
    const int rowA = blockIdx.x * 2;

    const float4* bf01  = (const float4*)(ws + BF01_OFF);
    const float4* bff   = (const float4*)(ws + BFF_OFF);
    const float4* act4  = (const float4*)(ws + ACT4_OFF);
    const int* phys   = (const int*)(ws + PHYS_OFF);
    const int* physr  = (const int*)(ws + PHYSR_OFF);
    const int* physo2 = (const int*)(ws + PHYSO2_OFF);

    const int tl = t & 127, th = t >> 7;
    const int b  = tl + th * 512;        // holdings {b+128m}
    const int a  = 2 * tl + th;          // write base

    const int wA0 = swz(2 * a), wA1 = swz(2 * a + 512);
    const int rd0 = swz(b), rd1 = swz(b + 128), rd2 = swz(b + 256), rd3 = swz(b + 384);
    const int zmem = swz(2 * t);
    const int u = t - 128;
    int za0 = 0, za1 = 0, za2 = 0, za3 = 0, zk0 = 0, zk1 = 0;
    if (t < 128) {
        int k0 = t >> 1;
        za0 = swz(512 + k0);       za1 = swz(512 + k0 + 64);
        za2 = swz(512 + k0 + 128); za3 = swz(512 + k0 + 192);
    } else {
        zk0 = swz(768 + u); zk1 = swz(896 + u);
    }

    float hA0, hA1, hA2, hA3, hB0, hB1, hB2, hB3;
    {
        const float* Xr0 = X + (size_t)rowA * 1024;
        const float* Xr1 = Xr0 + 1024;
        float s0 = scales[b], s1 = scales[b + 128], s2 = scales[b + 256], s3 = scales[b + 384];
        hA0 = Xr0[b] * s0; hA1 = Xr0[b + 128] * s1;
        hA2 = Xr0[b + 256] * s2; hA3 = Xr0[b + 384] * s3;
        hB0 = Xr1[b] * s0; hB1 = Xr1[b + 128] * s1;
        hB2 = Xr1[b + 256] * s2; hB3 = Xr1[b + 384] * s3;
    }

    int woff = 2304, roff = 3328;        // exchange double-buffer offsets
    const float4* ft = (const float4*)(ws + FTAB_OFF) + 2 * t;

    for (int d = 0; d < DEPTH; ++d) {
        for (int g = 0; g < 5; ++g) {
            float4 csA = ft[0], csB = ft[1]; ft += 512;
            // row A
            float g0 =  csA.x * hA0 + csA.y * hA2;
            float g2 = -csA.y * hA0 + csA.x * hA2;
            float g1 =  csA.z * hA1 + csA.w * hA3;
            float g3 = -csA.w * hA1 + csA.z * hA3;
            float fA0 =  csB.x * g0 + csB.y * g1;
            float fA2 = -csB.y * g0 + csB.x * g1;
            float fA1 =  csB.z * g2 + csB.w * g3;
            float fA3 = -csB.w * g2 + csB.z * g3;
            // row B
            float G0 =  csA.x * hB0 + csA.y * hB2;
            float G2 = -csA.y * hB0 + csA.x * hB2;
            float G1 =  csA.z * hB1 + csA.w * hB3;
            float G3 = -csA.w * hB1 + csA.z * hB3;
            float fB0 =  csB.x * G0 + csB.y * G1;
            float fB2 = -csB.y * G0 + csB.x * G1;
            float fB1 =  csB.z * G2 + csB.w * G3;
            float fB3 = -csB.w * G2 + csB.z * G3;
            *(float2*)(L0 + woff + wA0) = make_float2(fA0, fA1);
            *(float2*)(L0 + woff + wA1) = make_float2(fA2, fA3);
            *(float2*)(L1 + woff + wA0) = make_float2(fB0, fB1);
            *(float2*)(L1 + woff + wA1) = make_float2(fB2, fB3);
            { int tmp = woff; woff = roff; roff = tmp; }   // roff = just written
            __syncthreads();
            if (g < 4) {
                hA0 = L0[roff + rd0]; hA1 = L0[roff + rd1];
                hA2 = L0[roff + rd2]; hA3 = L0[roff + rd3];
                hB0 = L1[roff + rd0]; hB1 = L1[roff + rd1];
                hB2 = L1[roff + rd2]; hB3 = L1[roff + rd3];
            }
        }
        // ---- repack ----
        const float* z0 = L0 + roff;
        const float* z1 = L1 + roff;
        float2 mvA = *(const float2*)(z0 + zmem);
        float2 mvB = *(const float2*)(z1 + zmem);
        int2 pm = ((const int2*)(phys + d * 512))[t];
        L0[pm.x] = mvA.x; L0[pm.y] = mvA.y;
        L1[pm.x] = mvB.x; L1[pm.y] = mvB.y;
        int r0 = 0, r1 = 0;
        if (t < 128) {
            int k0 = t >> 1;
            float4 a0 = act4[d * 256 + k0];
            float4 a1 = act4[d * 256 + k0 + 64];
            float4 a2 = act4[d * 256 + k0 + 128];
            float4 a3 = act4[d * 256 + k0 + 192];
            float sgn = (t & 1) ? -1.0f : 1.0f;
            hA0 = actf(sgn * (z0[za0] + a0.x), a0.y, a0.z);
            hA1 = actf(sgn * (z0[za1] + a1.x), a1.y, a1.z);
            hA2 = actf(sgn * (z0[za2] + a2.x), a2.y, a2.z);
            hA3 = actf(sgn * (z0[za3] + a3.x), a3.y, a3.z);
            hB0 = actf(sgn * (z1[za0] + a0.x), a0.y, a0.z);
            hB1 = actf(sgn * (z1[za1] + a1.x), a1.y, a1.z);
            hB2 = actf(sgn * (z1[za2] + a2.x), a2.y, a2.z);
            hB3 = actf(sgn * (z1[za3] + a3.x), a3.y, a3.z);
        } else {
            hA0 = z0[zk0]; hA1 = z0[zk1];
            hB0 = z1[zk0]; hB1 = z1[zk1];
            r0 = physr[d * 256 + u];
            r1 = physr[d * 256 + u + 128];
        }
        __syncthreads();                 // mem scatter visible
        if (t >= 128) {
            hA2 = L0[r0]; hA3 = L0[r1];
            hB2 = L1[r0]; hB3 = L1[r1];
        }
    }

    // ---- stage sponge into natural layout (exchange region, offset 2304) ----
    L0[2304 + b] = hA0; L0[2304 + b + 128] = hA1;
    L0[2304 + b + 256] = hA2; L0[2304 + b + 384] = hA3;
    L1[2304 + b] = hB0; L1[2304 + b + 128] = hB1;
    L1[2304 + b + 256] = hB2; L1[2304 + b + 384] = hB3;
    __syncthreads();

    // ---- gather pre into 24 named scalars (no arrays -> no scratch) ----
    float vA0, vA1, vA2, vA3, vA4, vA5, vA6, vA7, vA8, vA9, vA10, vA11;
    float vB0, vB1, vB2, vB3, vB4, vB5, vB6, vB7, vB8, vB9, vB10, vB11;
    {
        int4 pg = ((const int4*)(physo2 + t * 12))[0];
        vA0 = L0[pg.x]; vA1 = L0[pg.y]; vA2 = L0[pg.z]; vA3 = L0[pg.w];
        vB0 = L1[pg.x]; vB1 = L1[pg.y]; vB2 = L1[pg.z]; vB3 = L1[pg.w];
        pg = ((const int4*)(physo2 + t * 12))[1];
        vA4 = L0[pg.x]; vA5 = L0[pg.y]; vA6 = L0[pg.z]; vA7 = L0[pg.w];
        vB4 = L1[pg.x]; vB5 = L1[pg.y]; vB6 = L1[pg.z]; vB7 = L1[pg.w];
        pg = ((const int4*)(physo2 + t * 12))[2];
        vA8 = L0[pg.x]; vA9 = L0[pg.y]; vA10 = L0[pg.z]; vA11 = L0[pg.w];
        vB8 = L1[pg.x]; vB9 = L1[pg.y]; vB10 = L1[pg.z]; vB11 = L1[pg.w];
    }
    __syncthreads();                     // all reads done before buf overwrite

    // ---- stages 0-1 in registers, write both rows' 3072-buffers ----
#define BF01_STEP(i, qA0, qA1, qA2, qA3, qB0, qB1, qB2, qB3)                        \
    {                                                                               \
        float4 c01 = bf01[(t * 3 + (i)) * 2];                                       \
        float4 c23 = bf01[(t * 3 + (i)) * 2 + 1];                                   \
        float g0 =  c01.x * qA0 + c01.y * qA2;                                      \
        float g2 = -c01.y * qA0 + c01.x * qA2;                                      \
        float g1 =  c01.z * qA1 + c01.w * qA3;                                      \
        float g3 = -c01.w * qA1 + c01.z * qA3;                                      \
        float y0 =  c23.x * g0 + c23.y * g1;                                        \
        float y2 = -c23.y * g0 + c23.x * g1;                                        \
        float y1 =  c23.z * g2 + c23.w * g3;                                        \
        float y3 = -c23.w * g2 + c23.z * g3;                                        \
        *(float2*)(L0 + 2 * t + 512 * (i))        = make_float2(y0, y1);            \
        *(float2*)(L0 + 2 * t + 512 * (i) + 1536) = make_float2(y2, y3);            \
        g0 =  c01.x * qB0 + c01.y * qB2;                                            \
        g2 = -c01.y * qB0 + c01.x * qB2;                                            \
        g1 =  c01.z * qB1 + c01.w * qB3;                                            \
        g3 = -c01.w * qB1 + c01.z * qB3;                                            \
        y0 =  c23.x * g0 + c23.y * g1;                                              \
        y2 = -c23.y * g0 + c23.x * g1;                                              \
        y1 =  c23.z * g2 + c23.w * g3;                                              \
        y3 = -c23.w * g2 + c23.z * g3;                                              \
        *(float2*)(L1 + 2 * t + 512 * (i))        = make_float2(y0, y1);            \
        *(float2*)(L1 + 2 * t + 512 * (i) + 1536) = make_float2(y2, y3);            \
    }
    BF01_STEP(0, vA0, vA1, vA2, vA3, vB0, vB1, vB2, vB3)
    BF01_STEP(1, vA4, vA5, vA6, vA7, vB4, vB5, vB6, vB7)
    BF01_STEP(2, vA8, vA9, vA10, vA11, vB8, vB9, vB10, vB11)
#undef BF01_STEP
    __syncthreads();

    // ---- fused pruned double-stages (2,3) (4,5) (6,7) (8,9) ----
#pragma unroll
    for (int f = 0; f < 4; ++f) {
        int P;
        if (f == 0) P = 3 * t;
        else { const int k = 8 - 2 * f;
               P = ((t >> (2 * f)) * (768 >> k)) + (t & ((256 >> k) - 1)); }
        int base = (P >> 1) + (P & 1) * 1536;
        float4 csS = bff[(f * 256 + t) * 2];
        float4 csT = bff[(f * 256 + t) * 2 + 1];
        float xA1p = L0[base], xA1q = L0[base + 384];
        float xA2p = L0[base + 768], xA2q = L0[base + 1152];
        float xB1p = L1[base], xB1q = L1[base + 384];
        float xB2p = L1[base + 768], xB2q = L1[base + 1152];
        float o1P =  csS.x * xA1p + csS.y * xA2p;
        float o2P = -csS.y * xA1p + csS.x * xA2p;
        float o1Q =  csS.z * xA1q + csS.w * xA2q;
        float o2Q = -csS.w * xA1q + csS.z * xA2q;
        float yA0 =  csT.x * o1P + csT.y * o1Q;
        float yA2 = -csT.y * o1P + csT.x * o1Q;
        float yA1 =  csT.z * o2P + csT.w * o2Q;
        float yA3 = -csT.w * o2P + csT.z * o2Q;
        o1P =  csS.x * xB1p + csS.y * xB2p;
        o2P = -csS.y * xB1p + csS.x * xB2p;
        o1Q =  csS.z * xB1q + csS.w * xB2q;
        o2Q = -csS.w * xB1q + csS.z * xB2q;
        float yB0 =  csT.x * o1P + csT.y * o1Q;
        float yB2 = -csT.y * o1P + csT.x * o1Q;
        float yB1 =  csT.z * o2P + csT.w * o2Q;
        float yB3 = -csT.w * o2P + csT.z * o2Q;
        __syncthreads();
        *(float2*)(L0 + 2 * P)        = make_float2(yA0, yA1);
        *(float2*)(L0 + 2 * P + 1536) = make_float2(yA2, yA3);
        *(float2*)(L1 + 2 * P)        = make_float2(yB0, yB1);
        *(float2*)(L1 + 2 * P + 1536) = make_float2(yB2, yB3);
        __syncthreads();
    }

    // ---- fused (10,11) + output store, both rows ----
    {
        int base = (t >> 1) + (t & 1) * 1536;
        float4 csS = bff[(4 * 256 + t) * 2];
        float4 csT = bff[(4 * 256 + t) * 2 + 1];
        float x1p = L0[base], x1q = L0[base + 384];
        float x2p = L0[base + 768], x2q = L0[base + 1152];
        float o1P =  csS.x * x1p + csS.y * x2p;
        float o2P = -csS.y * x1p + csS.x * x2p;
        float o1Q =  csS.z * x1q + csS.w * x2q;
        float o2Q = -csS.w * x1q + csS.z * x2q;
        *(float2*)(out + (size_t)rowA * 512 + 2 * t) =
            make_float2(csT.x * o1P + csT.y * o1Q, csT.z * o2P + csT.w * o2Q);
        x1p = L1[base]; x1q = L1[base + 384];
        x2p = L1[base + 768]; x2q = L1[base + 1152];
        o1P =  csS.x * x1p + csS.y * x2p;
        o2P = -csS.y * x1p + csS.x * x2p;
        o1Q =  csS.z * x1q + csS.w * x2q;
        o2Q = -csS.w * x1q + csS.z * x2q;
        *(float2*)(out + (size_t)(rowA + 1) * 512 + 2 * t) =
            make_float2(csT.x * o1P + csT.y * o1Q, csT.z * o2P + csT.w * o2Q);
    }
}

extern "C" void kernel_launch(void* const* d_in, const int* in_sizes, int n_in,
                              void* d_out, int out_size, void* d_ws, size_t ws_size,
                              hipStream_t stream) {
    const float* X          = (const float*)d_in[0];
    const float* scales     = (const float*)d_in[1];
    const float* angles     = (const float*)d_in[2];
    const float* act_bias   = (const float*)d_in[3];
    // d_in[4] act_activation — unused by the reference
    const float* act_curv   = (const float*)d_in[5];
    const float* bf_angles  = (const float*)d_in[6];
    // d_in[7] shuffle_perm — structural perfect shuffle, hardcoded
    const int*   recall_idx  = (const int*)d_in[8];
    const int*   out_mem_idx = (const int*)d_in[9];
    // d_in[10] bf_perm — structural perfect shuffle, hardcoded

    float* ws = (float*)d_ws;   // 462848 bytes used

    tab_precompute<<<200, 256, 0, stream>>>(angles, bf_angles, act_bias, act_curv, ws);
    phys_precompute<<<1, 1024, 0, stream>>>(recall_idx, out_mem_idx, ws);
    sponge_kernel<<<NB / 2, 256, 0, stream>>>(X, scales, ws, (float*)d_out);
}